// Round 5
// baseline (177.186 us; speedup 1.0000x reference)
//
#include <hip/hip_runtime.h>
#include <hip/hip_bf16.h>

// R5: single-exposed-latency fusion.
//  convert_w: W fp32 -> bf16 in MFMA fragment order (tiny, L2-resident).
//  fused_main: one block (512 thr) = one m-tile (16 pooled pixels) x all 512
//  channels. All 32 x-loads per thread issued back-to-back (131KB/block in
//  flight), BN+ReLU+pool -> bf16 y-tile in fragment order in LDS (16KB),
//  ONE barrier, then fragment GEMM: 8 waves x 32 outputs, no further barriers.

typedef short bf16x8 __attribute__((ext_vector_type(8)));
typedef float f32x4  __attribute__((ext_vector_type(4)));

constexpr int BB=16, CIN=512, COUT=256, HH=56, WW=56, HP=28, WP=28;
constexpr int MTILES  = (BB * HP * WP) / 16;    // 784
constexpr int WBLOCKS = (COUT * CIN / 8) / 256; // 64

__device__ __forceinline__ short f2bf(float f) {
    __hip_bfloat16 h = __float2bfloat16(f);
    return *reinterpret_cast<short*>(&h);
}

// wsw[(ot*16+ksg)*64 + lane] : W[o=ot*16+(lane&15)][k=ksg*32+(lane>>4)*8 + j]
__global__ __launch_bounds__(256)
void convert_w(const float* __restrict__ w, short* __restrict__ wsw) {
    int t    = blockIdx.x * 256 + threadIdx.x;   // [0, 16384)
    int lane = t & 63;
    int tile = t >> 6;                           // ot*16 + ksg
    int o    = (tile >> 4) * 16 + (lane & 15);
    int k    = (tile & 15) * 32 + (lane >> 4) * 8;
    const float4* src = reinterpret_cast<const float4*>(w + (size_t)o * CIN + k);
    float4 v0 = src[0], v1 = src[1];
    bf16x8 p;
    p[0]=f2bf(v0.x); p[1]=f2bf(v0.y); p[2]=f2bf(v0.z); p[3]=f2bf(v0.w);
    p[4]=f2bf(v1.x); p[5]=f2bf(v1.y); p[6]=f2bf(v1.z); p[7]=f2bf(v1.w);
    reinterpret_cast<bf16x8*>(wsw)[t] = p;
}

__global__ __launch_bounds__(512)
void fused_main(const float* __restrict__ x,  const float* __restrict__ bnw,
                const float* __restrict__ bnb, const float* __restrict__ bnm,
                const float* __restrict__ bnv, const short* __restrict__ wsw,
                float* __restrict__ out)
{
    // y-tile in MFMA fragment order: slot (ksg*64 + lane) holds
    // y[m=mt*16+(lane&15)][k=ksg*32+(lane>>4)*8 + j], j=0..7
    __shared__ __align__(16) short Ylds[16 * 64 * 8];   // 16 KB
    __shared__ float s_s[CIN];
    __shared__ float s_t[CIN];

    const int tid = threadIdx.x;
    const int mt  = blockIdx.x;
    const int l16 = tid & 15;            // pooled pixel within tile
    const int kg  = tid >> 4;            // 0..31 -> channels [kg*16, kg*16+16)

    const int m  = mt * 16 + l16;
    const int b  = m / (HP * WP);
    const int r  = m % (HP * WP);
    const int hp = r / WP;
    const int wp = r % WP;
    const float2* xr0 = reinterpret_cast<const float2*>(
        x + (size_t)b * CIN * HH * WW + (size_t)(2 * hp) * WW + 2 * wp);
    const float2* xr1 = xr0 + WW / 2;

    // ---- issue ALL 32 x-loads before any use (131KB/block in flight) ----
    float2 va[2][8], vb[2][8];
    #pragma unroll
    for (int h = 0; h < 2; h++) {
        const int cb = (kg * 2 + h) * 8;
        #pragma unroll
        for (int j = 0; j < 8; j++) {
            va[h][j] = xr0[(size_t)(cb + j) * (HH * WW / 2)];
            vb[h][j] = xr1[(size_t)(cb + j) * (HH * WW / 2)];
        }
    }

    // BN table (512 channels, 512 threads) — latency hides under x-loads
    {
        float inv = rsqrtf(bnv[tid] + 1e-5f);
        float s = bnw[tid] * inv;
        s_s[tid] = s;
        s_t[tid] = bnb[tid] - bnm[tid] * s;
    }
    __syncthreads();                     // table ready (drains x-loads too)

    // ---- BN + ReLU + 2x2 pool -> bf16 -> Ylds (fragment order) ----
    #pragma unroll
    for (int h = 0; h < 2; h++) {
        const int k8 = kg * 2 + h;
        const int cb = k8 * 8;
        bf16x8 p;
        #pragma unroll
        for (int j = 0; j < 8; j++) {
            float s = s_s[cb + j], t = s_t[cb + j];
            float y0 = fmaxf(fmaf(va[h][j].x, s, t), 0.f);
            float y1 = fmaxf(fmaf(va[h][j].y, s, t), 0.f);
            float y2 = fmaxf(fmaf(vb[h][j].x, s, t), 0.f);
            float y3 = fmaxf(fmaf(vb[h][j].y, s, t), 0.f);
            p[j] = f2bf((y0 + y1 + y2 + y3) * 0.25f);
        }
        const int idx = (k8 >> 2) * 64 + (k8 & 3) * 16 + l16;
        *reinterpret_cast<bf16x8*>(&Ylds[idx * 8]) = p;
    }
    __syncthreads();                     // sole GEMM barrier

    // ---- fragment GEMM: wave wv -> outputs [wv*32, wv*32+32) ----
    const int lane = tid & 63;
    const int wv   = tid >> 6;           // 0..7
    const int q    = lane >> 4;

    const bf16x8* yfp = reinterpret_cast<const bf16x8*>(Ylds);
    const bf16x8* wfp = reinterpret_cast<const bf16x8*>(wsw);

    f32x4 acc[2];
    acc[0] = (f32x4){0.f, 0.f, 0.f, 0.f};
    acc[1] = (f32x4){0.f, 0.f, 0.f, 0.f};

    #pragma unroll
    for (int ksg = 0; ksg < 16; ksg++) {
        bf16x8 yf = yfp[ksg * 64 + lane];             // ds_read_b128
        #pragma unroll
        for (int ns = 0; ns < 2; ns++) {
            const int ot = wv * 2 + ns;
            bf16x8 wf = wfp[(ot * 16 + ksg) * 64 + lane];  // 1KB coalesced
            acc[ns] = __builtin_amdgcn_mfma_f32_16x16x32_bf16(wf, yf, acc[ns], 0, 0, 0);
        }
    }

    // ---- epilogue: D col = m = lane&15 (== l16, so b/r reusable) ----
    const int addrm = b * (COUT * HP * WP) + r;
    #pragma unroll
    for (int ns = 0; ns < 2; ns++)
        #pragma unroll
        for (int rg = 0; rg < 4; rg++) {
            const int o = wv * 32 + ns * 16 + q * 4 + rg;
            out[(size_t)addrm + (size_t)o * (HP * WP)] = acc[ns][rg];
        }
}

extern "C" void kernel_launch(void* const* d_in, const int* in_sizes, int n_in,
                              void* d_out, int out_size, void* d_ws, size_t ws_size,
                              hipStream_t stream) {
    const float* x   = (const float*)d_in[0];
    const float* bnw = (const float*)d_in[1];
    const float* bnb = (const float*)d_in[2];
    const float* bnm = (const float*)d_in[3];
    const float* bnv = (const float*)d_in[4];
    const float* w   = (const float*)d_in[5];
    float* out = (float*)d_out;
    short* wsw = (short*)d_ws;                  // 256 KB swizzled bf16 weights

    convert_w<<<WBLOCKS, 256, 0, stream>>>(w, wsw);
    fused_main<<<MTILES, 512, 0, stream>>>(x, bnw, bnb, bnm, bnv, wsw, out);
}